// Round 9
// baseline (437.988 us; speedup 1.0000x reference)
//
#include <hip/hip_runtime.h>
#include <hip/hip_bf16.h>

// out[b,s,o] = sum_k x[b,s,k] * W[o,k] + bias[o],  W[o,k] = sum_d codebook[idx[o,d]] * rot[k,d]
// bf16 path: dequant+convert, GEMM1 (W = Wr @ R^T, bf16 out), GEMM2 (out = X @ W^T + bias, f32).
// R9: R8 chassis (256x256, BK=64, 8 waves 2Mx4N, 16x16x32, 1 barrier/phase, stage 1 half-tile
// per phase, counted vmcnt(4)) + FENCED read prefetch: each phase's fragments are ds_read one
// phase early, pinned with sched_barrier(0) on both sides so the scheduler cannot sink the
// reads to first-use (rule 18: bare inline-asm lgkmcnt binds nothing; without the pin, R5-R8's
// "prefetch" never changed the emitted order -> reads drained serially before each MFMA
// cluster -> the stuck 44% MfmaUtil). Reads now drain under the previous MFMA cluster.
// Hazard audit: each wave's per-phase lgkm(0) drains ALL its LDS reads (incl. prefetched)
// before it reaches the next barrier, so post-barrier stages never overwrite live regions:
//   ph0/ph1 stage A0,A1(T+1) -> idle buf (last read tile T-1, drained pre-BAR(T.ph0));
//   ph2/ph3 stage B0,B1(T+2) -> current-buf B-region (B reads all happen in ph0, drained by
//   each wave's ph0/ph1 lgkm(0), sequenced by BAR(ph2)).
// vmcnt logic identical to R8: vmcnt(4) pre-BAR(ph0) certifies A(T)+B(T) landed, leaves the
// 4 youngest (B-next) in flight; vmcnt(0) on the last tile.

typedef __attribute__((ext_vector_type(8))) __bf16 bf16x8;
typedef __attribute__((ext_vector_type(4))) float f32x4;

#define GLOAD_LDS16(g, l)                                                        \
  __builtin_amdgcn_global_load_lds((__attribute__((address_space(1))) void*)(g), \
                                   (__attribute__((address_space(3))) void*)(l), \
                                   16, 0, 0)

// ---------------- conversion kernels ----------------

__global__ __launch_bounds__(256) void cvt_f32_bf16(const float* __restrict__ in,
                                                    __hip_bfloat16* __restrict__ out, int n4) {
  int i = blockIdx.x * 256 + threadIdx.x;
  if (i >= n4) return;
  float4 v = *(const float4*)(in + (size_t)i * 4);
  union { __hip_bfloat16 h[4]; ushort4 u; } o;
  o.h[0] = __float2bfloat16(v.x);
  o.h[1] = __float2bfloat16(v.y);
  o.h[2] = __float2bfloat16(v.z);
  o.h[3] = __float2bfloat16(v.w);
  *(ushort4*)((unsigned short*)out + (size_t)i * 4) = o.u;
}

__global__ __launch_bounds__(256) void dequant_bf16(const int* __restrict__ idx,
                                                    const float* __restrict__ cb,
                                                    __hip_bfloat16* __restrict__ out, int n4) {
  __shared__ __hip_bfloat16 scb[16];
  if (threadIdx.x < 16) scb[threadIdx.x] = __float2bfloat16(cb[threadIdx.x]);
  __syncthreads();
  int i = blockIdx.x * 256 + threadIdx.x;
  if (i >= n4) return;
  int4 v = *(const int4*)(idx + (size_t)i * 4);
  union { __hip_bfloat16 h[4]; ushort4 u; } o;
  o.h[0] = scb[v.x & 15];
  o.h[1] = scb[v.y & 15];
  o.h[2] = scb[v.z & 15];
  o.h[3] = scb[v.w & 15];
  *(ushort4*)((unsigned short*)out + (size_t)i * 4) = o.u;
}

// ---------------- 256^2 4-phase (1-barrier, fenced-prefetch) NT bf16 GEMM ----------------

template <bool OUT_BF16>
__global__ __launch_bounds__(512, 2) void gemm256(const __hip_bfloat16* __restrict__ A,
                                                  const __hip_bfloat16* __restrict__ B,
                                                  void* __restrict__ Cv,
                                                  const float* __restrict__ bias,
                                                  int M, int N, int K) {
  __shared__ __align__(16) char smem[131072];

  const int nbn = N >> 8;
  const int nwg = (M >> 8) * nbn;
  const int bid0 = blockIdx.x;
  const int cpx = nwg >> 3;  // nwg % 8 == 0 for our shapes -> bijective XCD swizzle
  const int bid = (bid0 & 7) * cpx + (bid0 >> 3);
  const int m0 = (bid / nbn) << 8;
  const int n0 = (bid % nbn) << 8;

  const int tid = (int)threadIdx.x;
  const int lane = tid & 63;
  const int w = tid >> 6;   // wave 0..7
  const int wr = w >> 2;    // 0..1 -> 128 rows
  const int wc = w & 3;     // 0..3 -> 64 cols
  const int fr = lane & 15;
  const int fq = lane >> 4;

  // staging lane pattern: srow = row within 8-row stripe, scol = inverse-swizzled col
  const int srow = lane >> 3;                 // 0..7
  const int scol = ((lane & 7) ^ srow) << 3;  // element offset within 64-col row

  const __hip_bfloat16* Ab = A + (size_t)m0 * K;
  const __hip_bfloat16* Bb = B + (size_t)n0 * K;

  const int NT = K >> 6;

  f32x4 acc[8][4];
#pragma unroll
  for (int i = 0; i < 8; ++i)
#pragma unroll
    for (int j = 0; j < 4; ++j) acc[i][j] = (f32x4){0.f, 0.f, 0.f, 0.f};

  // stage half-tile s = 4*t + kind (kind: 0=A-half0, 1=A-half1, 2=B-half0, 3=B-half1)
  auto stage = [&](int s) {
    const int t = s >> 2, kind = s & 3;
    const __hip_bfloat16* g = (kind < 2) ? Ab : Bb;
    char* region = smem + ((kind < 2) ? 0 : 65536) + (t & 1) * 32768 + (kind & 1) * 16384;
    const int grow = (kind & 1) * 128 + w * 16 + srow;
    const int k0 = t << 6;
#pragma unroll
    for (int j = 0; j < 2; ++j)
      GLOAD_LDS16(g + (size_t)(grow + j * 8) * K + (k0 + scol), region + w * 2048 + j * 1024);
  };

  const int sw = (fr & 7) << 4;  // read-side swizzle XOR (row&7 == fr&7 for all frag rows)

  auto ldA = [&](int b, int mh, int mf, int kk) -> bf16x8 {
    const int row = wr * 128 + mh * 64 + mf * 16 + fr;
    const int byte = b * 32768 + row * 128 + ((kk * 64 + fq * 16) ^ sw);
    return *(const bf16x8*)(smem + byte);
  };
  auto ldB = [&](int b, int nf, int kk) -> bf16x8 {
    const int row = wc * 64 + nf * 16 + fr;
    const int byte = 65536 + b * 32768 + row * 128 + ((kk * 64 + fq * 16) ^ sw);
    return *(const bf16x8*)(smem + byte);
  };

#define FENCE() __builtin_amdgcn_sched_barrier(0)

  // prologue: tile0 fully + B(1) (12 gloads/wave); loop ph0's vmcnt+BAR certifies tile0
  stage(0); stage(1); stage(2); stage(3);
  stage(6); stage(7);

  bf16x8 afA[4], afB[4], bk0[4], bk1[4];

  for (int T = 0; T < NT; ++T) {
    const int b = T & 1;
    const bool pf1 = (T + 1 < NT);
    const bool pf2 = (T + 2 < NT);

    // ---- ph0: vmcnt certify; BAR; stage A0(T+1); serial reads (afA,bk0); drain;
    //           fenced prefetch ph1 reads (afB,bk1); MFMA acc[0-3] k0
    if (T + 1 == NT) {
      asm volatile("s_waitcnt vmcnt(0)" ::: "memory");
    } else {
      asm volatile("s_waitcnt vmcnt(4)" ::: "memory");
    }
    __builtin_amdgcn_s_barrier();
    if (pf1) stage(4 * (T + 1) + 0);
#pragma unroll
    for (int mf = 0; mf < 4; ++mf) afA[mf] = ldA(b, 0, mf, 0);
#pragma unroll
    for (int nf = 0; nf < 4; ++nf) bk0[nf] = ldB(b, nf, 0);
    FENCE();
    asm volatile("s_waitcnt lgkmcnt(0)");
    FENCE();
#pragma unroll
    for (int mf = 0; mf < 4; ++mf) afB[mf] = ldA(b, 0, mf, 1);  // prefetch ph1
#pragma unroll
    for (int nf = 0; nf < 4; ++nf) bk1[nf] = ldB(b, nf, 1);     // prefetch ph1
    FENCE();
    __builtin_amdgcn_s_setprio(1);
#pragma unroll
    for (int nf = 0; nf < 4; ++nf)
#pragma unroll
      for (int mf = 0; mf < 4; ++mf)
        acc[mf][nf] = __builtin_amdgcn_mfma_f32_16x16x32_bf16(afA[mf], bk0[nf], acc[mf][nf], 0, 0, 0);
    __builtin_amdgcn_s_setprio(0);

    // ---- ph1: BAR; stage A1(T+1); drain prefetched (afB,bk1);
    //           fenced prefetch ph2 reads (afA = A(m1,k0)); MFMA acc[0-3] k1
    __builtin_amdgcn_s_barrier();
    if (pf1) stage(4 * (T + 1) + 1);
    asm volatile("s_waitcnt lgkmcnt(0)");
    FENCE();
#pragma unroll
    for (int mf = 0; mf < 4; ++mf) afA[mf] = ldA(b, 1, mf, 0);  // prefetch ph2
    FENCE();
    __builtin_amdgcn_s_setprio(1);
#pragma unroll
    for (int nf = 0; nf < 4; ++nf)
#pragma unroll
      for (int mf = 0; mf < 4; ++mf)
        acc[mf][nf] = __builtin_amdgcn_mfma_f32_16x16x32_bf16(afB[mf], bk1[nf], acc[mf][nf], 0, 0, 0);
    __builtin_amdgcn_s_setprio(0);

    // ---- ph2: BAR; stage B0(T+2) (all B reads of buf b drained by every wave's ph0/ph1
    //           lgkm(0), sequenced by this barrier); drain afA; fenced prefetch ph3 reads
    //           (afB = A(m1,k1)); MFMA acc[4-7] k0
    __builtin_amdgcn_s_barrier();
    if (pf2) stage(4 * (T + 2) + 2);
    asm volatile("s_waitcnt lgkmcnt(0)");
    FENCE();
#pragma unroll
    for (int mf = 0; mf < 4; ++mf) afB[mf] = ldA(b, 1, mf, 1);  // prefetch ph3
    FENCE();
    __builtin_amdgcn_s_setprio(1);
#pragma unroll
    for (int nf = 0; nf < 4; ++nf)
#pragma unroll
      for (int mf = 0; mf < 4; ++mf)
        acc[4 + mf][nf] = __builtin_amdgcn_mfma_f32_16x16x32_bf16(afA[mf], bk0[nf], acc[4 + mf][nf], 0, 0, 0);
    __builtin_amdgcn_s_setprio(0);

    // ---- ph3: BAR; stage B1(T+2); drain afB; MFMA acc[4-7] k1 (no prefetch: T+1 ph0's
    //           data is certified only by its own vmcnt+BAR)
    __builtin_amdgcn_s_barrier();
    if (pf2) stage(4 * (T + 2) + 3);
    asm volatile("s_waitcnt lgkmcnt(0)");
    FENCE();
    __builtin_amdgcn_s_setprio(1);
#pragma unroll
    for (int nf = 0; nf < 4; ++nf)
#pragma unroll
      for (int mf = 0; mf < 4; ++mf)
        acc[4 + mf][nf] = __builtin_amdgcn_mfma_f32_16x16x32_bf16(afB[mf], bk1[nf], acc[4 + mf][nf], 0, 0, 0);
    __builtin_amdgcn_s_setprio(0);
    // next iteration's ph0 vmcnt+barrier closes the tile
  }
#undef FENCE

  // ---- epilogue: C/D layout col = lane&15 (n-side), row = fq*4 + v (m-side)
  if constexpr (OUT_BF16) {
    __hip_bfloat16* C = (__hip_bfloat16*)Cv;
#pragma unroll
    for (int mi = 0; mi < 8; ++mi)
#pragma unroll
      for (int ni = 0; ni < 4; ++ni) {
        const size_t row = (size_t)(m0 + wr * 128 + (mi >> 2) * 64 + (mi & 3) * 16 + fq * 4);
        const int col = n0 + wc * 64 + ni * 16 + fr;
#pragma unroll
        for (int v = 0; v < 4; ++v) C[(row + v) * N + col] = __float2bfloat16(acc[mi][ni][v]);
      }
  } else {
    float* C = (float*)Cv;
    float bv[4];
#pragma unroll
    for (int ni = 0; ni < 4; ++ni) bv[ni] = bias[n0 + wc * 64 + ni * 16 + fr];
#pragma unroll
    for (int mi = 0; mi < 8; ++mi)
#pragma unroll
      for (int ni = 0; ni < 4; ++ni) {
        const size_t row = (size_t)(m0 + wr * 128 + (mi >> 2) * 64 + (mi & 3) * 16 + fq * 4);
        const int col = n0 + wc * 64 + ni * 16 + fr;
#pragma unroll
        for (int v = 0; v < 4; ++v) C[(row + v) * N + col] = acc[mi][ni][v] + bv[ni];
      }
  }
}

// ---------------- launch ----------------

extern "C" void kernel_launch(void* const* d_in, const int* in_sizes, int n_in,
                              void* d_out, int out_size, void* d_ws, size_t ws_size,
                              hipStream_t stream) {
  const float* x = (const float*)d_in[0];        // [B,S,D] = [4,2048,4096] f32
  const int* indices = (const int*)d_in[1];      // [O,D] = [4096,4096] i32
  const float* codebook = (const float*)d_in[2]; // [16] f32
  const float* rot = (const float*)d_in[3];      // [K,D] = [4096,4096] f32
  const float* bias = (const float*)d_in[4];     // [O] f32
  float* out = (float*)d_out;                    // [B*S, O] f32

  const int D = 4096, O = 4096;
  const int M = in_sizes[0] / D;  // 8192

  char* ws = (char*)d_ws;
  __hip_bfloat16* Xb = (__hip_bfloat16*)ws;                          // 64MB: [M,D] bf16
  __hip_bfloat16* Rb = (__hip_bfloat16*)(ws + ((size_t)64 << 20));   // 32MB: [K,D] bf16
  __hip_bfloat16* Wr = (__hip_bfloat16*)(ws + ((size_t)96 << 20));   // 32MB: [O,D] bf16
  __hip_bfloat16* Wb = (__hip_bfloat16*)(ws + ((size_t)128 << 20));  // 32MB: [O,K] bf16

  cvt_f32_bf16<<<(M * D / 4 + 255) / 256, 256, 0, stream>>>(x, Xb, M * D / 4);
  cvt_f32_bf16<<<(4096 * 4096 / 4 + 255) / 256, 256, 0, stream>>>(rot, Rb, 4096 * 4096 / 4);
  dequant_bf16<<<(4096 * 4096 / 4 + 255) / 256, 256, 0, stream>>>(indices, codebook, Wr,
                                                                  4096 * 4096 / 4);

  // GEMM1: Wb[o,k] = sum_d Wr[o,d] * Rb[k,d]   (4096^3, bf16 out)
  gemm256<true><<<dim3((O / 256) * (4096 / 256)), 512, 0, stream>>>(Wr, Rb, Wb, nullptr, O, 4096,
                                                                    D);
  // GEMM2: out[m,o] = sum_k Xb[m,k] * Wb[o,k] + bias[o]   (8192x4096x4096, f32 out)
  gemm256<false><<<dim3((M / 256) * (O / 256)), 512, 0, stream>>>(Xb, Wb, out, bias, M, O, 4096);
}